// Round 1
// baseline (340.562 us; speedup 1.0000x reference)
//
#include <hip/hip_runtime.h>
#include <cmath>

// Problem constants (from setup_inputs)
constexpr int B     = 32;
constexpr int L     = 2048;
constexpr int D_CTX = 512;
constexpr int D_Q   = 1024;
constexpr int H     = 256;
constexpr int PRUNE_L = -3;
constexpr int PRUNE_R = 3;
constexpr int W = PRUNE_R - PRUNE_L + 1;  // 7-position window

// ---------------------------------------------------------------------------
// Kernel A: per-batch GMM stats.
//   h = tanh(query @ Wq + bq)  [H]
//   stat = h @ Ws + bs         [3]
//   alpha=exp(s0), beta=exp(s1), kappa=exp(s2)+kappa_prev, center=rint(kappa)
// grid = B, block = H (one thread per hidden unit)
// ---------------------------------------------------------------------------
__global__ __launch_bounds__(H) void stats_kernel(
    const float* __restrict__ query,      // [B, D_Q]
    const float* __restrict__ kappa_prev, // [B, 1]
    const float* __restrict__ Wq,         // [D_Q, H] row-major
    const float* __restrict__ bq,         // [H]
    const float* __restrict__ Ws,         // [H, 3] row-major
    const float* __restrict__ bs,         // [3]
    float* __restrict__ stats)            // [B, 4] = {alpha, beta, kappa, center}
{
    const int b = blockIdx.x;
    const int j = threadIdx.x;

    __shared__ float q_sh[D_Q];
    for (int k = j; k < D_Q; k += H) q_sh[k] = query[b * D_Q + k];
    __syncthreads();

    float acc = bq[j];
#pragma unroll 8
    for (int k = 0; k < D_Q; ++k) acc += q_sh[k] * Wq[k * H + j];  // coalesced over j
    const float hj = tanhf(acc);

    __shared__ float red[H];
    float stat[3];
    for (int i = 0; i < 3; ++i) {
        red[j] = hj * Ws[j * 3 + i];
        __syncthreads();
        for (int s = H / 2; s > 0; s >>= 1) {
            if (j < s) red[j] += red[j + s];
            __syncthreads();
        }
        stat[i] = red[0];
        __syncthreads();  // protect red[0] before next iteration overwrites
    }

    if (j == 0) {
        const float alpha  = expf(stat[0] + bs[0]);
        const float beta   = expf(stat[1] + bs[1]);
        const float kappa  = expf(stat[2] + bs[2]) + kappa_prev[b];
        const float center = rintf(kappa);  // round-half-even, matches jnp.round
        stats[b * 4 + 0] = alpha;
        stats[b * 4 + 1] = beta;
        stats[b * 4 + 2] = kappa;
        stats[b * 4 + 3] = center;
    }
}

// ---------------------------------------------------------------------------
// Kernel B: MLP score + unnormalized posterior, ONLY at the 7 window positions.
//   comb = [ctx[b,l,:], query[b,:]]                     (1536)
//   score = tanh(comb @ W1 + b1) @ W2 + b2
//   post  = exp(score) * alpha * exp(-beta * (l-kappa)^2)
// grid = (W, B), block = H
// ---------------------------------------------------------------------------
__global__ __launch_bounds__(H) void score_kernel(
    const float* __restrict__ query,  // [B, D_Q]
    const float* __restrict__ ctx,    // [B, L, D_CTX]
    const float* __restrict__ W1,     // [D_CTX+D_Q, H] row-major
    const float* __restrict__ b1,     // [H]
    const float* __restrict__ W2,     // [H, 1]
    const float* __restrict__ b2,     // [1]
    const float* __restrict__ stats,  // [B, 4]
    float* __restrict__ post)         // [B, W]
{
    const int t = blockIdx.x;  // window slot 0..6
    const int b = blockIdx.y;
    const int j = threadIdx.x;

    const float alpha  = stats[b * 4 + 0];
    const float beta   = stats[b * 4 + 1];
    const float kappa  = stats[b * 4 + 2];
    const int   center = (int)stats[b * 4 + 3];
    const int   l      = center + PRUNE_L + t;

    if (l < 0 || l >= L) {              // outside the sequence: posterior = 0
        if (j == 0) post[b * W + t] = 0.0f;
        return;
    }

    __shared__ float comb[D_CTX + D_Q];  // 1536 floats = 6 KB
    const size_t ctx_off = ((size_t)b * L + (size_t)l) * D_CTX;
    for (int k = j; k < D_CTX; k += H) comb[k]         = ctx[ctx_off + k];
    for (int k = j; k < D_Q;   k += H) comb[D_CTX + k] = query[b * D_Q + k];
    __syncthreads();

    float acc = b1[j];
#pragma unroll 8
    for (int k = 0; k < D_CTX + D_Q; ++k) acc += comb[k] * W1[k * H + j];  // LDS broadcast + coalesced W1
    const float sj = tanhf(acc) * W2[j];

    __shared__ float red[H];
    red[j] = sj;
    __syncthreads();
    for (int s = H / 2; s > 0; s >>= 1) {
        if (j < s) red[j] += red[j + s];
        __syncthreads();
    }

    if (j == 0) {
        const float score = red[0] + b2[0];
        const float diff  = (float)l - kappa;
        const float prior = alpha * expf(-beta * diff * diff);
        post[b * W + t] = expf(score) * prior;
    }
}

// ---------------------------------------------------------------------------
// Kernel C: normalize posterior over the window, write p_ctx (mostly zeros)
// and expected_ctx = sum_t p_t * ctx[b, l_t, :].
// grid = B, block = H
// ---------------------------------------------------------------------------
__global__ __launch_bounds__(H) void combine_kernel(
    const float* __restrict__ ctx,    // [B, L, D_CTX]
    const float* __restrict__ stats,  // [B, 4]
    const float* __restrict__ post,   // [B, W]
    float* __restrict__ out_e,        // [B, D_CTX]
    float* __restrict__ out_p)        // [B, L]
{
    const int b = blockIdx.x;
    const int j = threadIdx.x;

    __shared__ float p_sh[W];
    __shared__ int   l_sh[W];
    if (j == 0) {
        const int center = (int)stats[b * 4 + 3];
        float sum = 0.0f;
        for (int t = 0; t < W; ++t) sum += post[b * W + t];
        const float inv = 1.0f / sum;  // sum==0 -> NaN, same as reference
        for (int t = 0; t < W; ++t) {
            p_sh[t] = post[b * W + t] * inv;
            l_sh[t] = center + PRUNE_L + t;
        }
    }
    __syncthreads();

    // p_ctx row: zeros everywhere (d_out is poisoned!), then scatter window
    for (int k = j; k < L; k += H) out_p[b * L + k] = 0.0f;
    __syncthreads();  // order zero-fill before scatter within the block
    if (j < W) {
        const int l = l_sh[j];
        if (l >= 0 && l < L) out_p[b * L + l] = p_sh[j];
    }

    // expected_ctx: 7-term weighted sum of ctx rows
    for (int d = j; d < D_CTX; d += H) {
        float acc = 0.0f;
#pragma unroll
        for (int t = 0; t < W; ++t) {
            const int l = l_sh[t];
            if (l >= 0 && l < L)
                acc += p_sh[t] * ctx[((size_t)b * L + (size_t)l) * D_CTX + d];
        }
        out_e[b * D_CTX + d] = acc;
    }
}

extern "C" void kernel_launch(void* const* d_in, const int* in_sizes, int n_in,
                              void* d_out, int out_size, void* d_ws, size_t ws_size,
                              hipStream_t stream) {
    const float* query      = (const float*)d_in[0];
    const float* ctx        = (const float*)d_in[1];
    const float* kappa_prev = (const float*)d_in[2];
    const float* Wq         = (const float*)d_in[3];
    const float* bq         = (const float*)d_in[4];
    const float* Ws         = (const float*)d_in[5];
    const float* bs         = (const float*)d_in[6];
    const float* W1         = (const float*)d_in[7];
    const float* b1         = (const float*)d_in[8];
    const float* W2         = (const float*)d_in[9];
    const float* b2         = (const float*)d_in[10];

    float* out   = (float*)d_out;
    float* out_e = out;              // [B, D_CTX] — first return value
    float* out_p = out + B * D_CTX;  // [B, L]     — second return value

    float* stats = (float*)d_ws;     // [B, 4]
    float* post  = stats + B * 4;    // [B, W]

    stats_kernel<<<B, H, 0, stream>>>(query, kappa_prev, Wq, bq, Ws, bs, stats);
    score_kernel<<<dim3(W, B), H, 0, stream>>>(query, ctx, W1, b1, W2, b2, stats, post);
    combine_kernel<<<B, H, 0, stream>>>(ctx, stats, post, out_e, out_p);
}

// Round 2
// 248.972 us; speedup vs baseline: 1.3679x; 1.3679x over previous
//
#include <hip/hip_runtime.h>
#include <cmath>

// Problem constants (from setup_inputs)
constexpr int B     = 32;
constexpr int L     = 2048;
constexpr int D_CTX = 512;
constexpr int D_Q   = 1024;
constexpr int H     = 256;
constexpr int PRUNE_L = -3;
constexpr int PRUNE_R = 3;
constexpr int W = PRUNE_R - PRUNE_L + 1;  // 7-position window

// ---------------------------------------------------------------------------
// Kernel A: per-batch GMM stats + query-half of the MLP hidden pre-activation.
//   h      = tanh(query @ Wq + bq)                [H]
//   stat   = h @ Ws + bs                          [3] -> alpha/beta/kappa/center
//   qpart  = query @ W1[D_CTX:, :]                [H]  (hoisted out of window loop)
// grid = B, block = 1024.
// Thread layout: jg = tid&63 (float4 of 4 consecutive j), kc = tid>>6 (16 K-chunks
// of 64). Each wave has one kc and all 64 jg -> W loads perfectly coalesced
// (16B/lane), q_sh[k] is wave-uniform (LDS broadcast, free).
// ---------------------------------------------------------------------------
__global__ __launch_bounds__(1024) void stats_qpart_kernel(
    const float* __restrict__ query,      // [B, D_Q]
    const float* __restrict__ kappa_prev, // [B, 1]
    const float* __restrict__ Wq,         // [D_Q, H] row-major
    const float* __restrict__ bq,         // [H]
    const float* __restrict__ Ws,         // [H, 3] row-major
    const float* __restrict__ bs,         // [3]
    const float* __restrict__ W1,         // [D_CTX+D_Q, H] row-major
    float* __restrict__ stats,            // [B, 4] = {alpha, beta, kappa, center}
    float* __restrict__ qpart)            // [B, H]
{
    const int b   = blockIdx.x;
    const int tid = threadIdx.x;
    const int jg  = tid & 63;   // float4 column group: j = 4*jg .. 4*jg+3
    const int kc  = tid >> 6;   // K-chunk 0..15 (64 k's each)

    __shared__ float  q_sh[D_Q];            // 4 KB
    __shared__ float4 part[16][64];         // 16 KB K-split partials
    __shared__ float  h_sh[H];              // 1 KB
    __shared__ float  red[H];               // 1 KB

    for (int k = tid; k < D_Q; k += 1024) q_sh[k] = query[b * D_Q + k];
    __syncthreads();

    // ---- h = tanh(query @ Wq + bq) --------------------------------------
    {
        const float4* Wv = (const float4*)Wq;   // row k = 64 float4's
        float4 acc = make_float4(0.f, 0.f, 0.f, 0.f);
        const int k0 = kc * 64;
#pragma unroll 8
        for (int k = k0; k < k0 + 64; ++k) {
            const float  qk = q_sh[k];
            const float4 w  = Wv[k * 64 + jg];
            acc.x += qk * w.x; acc.y += qk * w.y;
            acc.z += qk * w.z; acc.w += qk * w.w;
        }
        part[kc][jg] = acc;
    }
    __syncthreads();
    for (int s = 8; s > 0; s >>= 1) {   // 16-way K-chunk reduce
        if (kc < s) {
            float4 a = part[kc][jg], c = part[kc + s][jg];
            a.x += c.x; a.y += c.y; a.z += c.z; a.w += c.w;
            part[kc][jg] = a;
        }
        __syncthreads();
    }
    // part[0] is 256 contiguous floats, float index == j
    if (tid < H) h_sh[tid] = tanhf(((const float*)part)[tid] + bq[tid]);
    __syncthreads();

    // ---- stat[i] = sum_j h[j] * Ws[j][i] --------------------------------
    float stat[3];
    for (int i = 0; i < 3; ++i) {
        if (tid < H) red[tid] = h_sh[tid] * Ws[tid * 3 + i];
        __syncthreads();
        for (int s = H / 2; s > 0; s >>= 1) {
            if (tid < s) red[tid] += red[tid + s];
            __syncthreads();
        }
        stat[i] = red[0];
        __syncthreads();
    }

    // ---- qpart = query @ W1[D_CTX:, :] ----------------------------------
    {
        const float4* Wv = (const float4*)(W1 + (size_t)D_CTX * H);
        float4 acc = make_float4(0.f, 0.f, 0.f, 0.f);
        const int k0 = kc * 64;
#pragma unroll 8
        for (int k = k0; k < k0 + 64; ++k) {
            const float  qk = q_sh[k];
            const float4 w  = Wv[k * 64 + jg];
            acc.x += qk * w.x; acc.y += qk * w.y;
            acc.z += qk * w.z; acc.w += qk * w.w;
        }
        part[kc][jg] = acc;
    }
    __syncthreads();
    for (int s = 8; s > 0; s >>= 1) {
        if (kc < s) {
            float4 a = part[kc][jg], c = part[kc + s][jg];
            a.x += c.x; a.y += c.y; a.z += c.z; a.w += c.w;
            part[kc][jg] = a;
        }
        __syncthreads();
    }
    if (tid < 64) ((float4*)qpart)[b * 64 + tid] = part[0][tid];

    if (tid == 0) {
        const float alpha  = expf(stat[0] + bs[0]);
        const float beta   = expf(stat[1] + bs[1]);
        const float kappa  = expf(stat[2] + bs[2]) + kappa_prev[b];
        const float center = rintf(kappa);  // round-half-even == jnp.round
        stats[b * 4 + 0] = alpha;
        stats[b * 4 + 1] = beta;
        stats[b * 4 + 2] = kappa;
        stats[b * 4 + 3] = center;
    }
}

// ---------------------------------------------------------------------------
// Kernel B: MLP score + unnormalized posterior at the 7 window positions.
//   score = tanh(ctx_row @ W1[:D_CTX] + qpart + b1) @ W2 + b2
//   post  = exp(score) * alpha * exp(-beta * (l-kappa)^2)
// grid = (W, B), block = 512: jg = tid&63 (float4 j), kc = tid>>6 (8 chunks of 64 k)
// ---------------------------------------------------------------------------
__global__ __launch_bounds__(512) void score_kernel(
    const float* __restrict__ ctx,    // [B, L, D_CTX]
    const float* __restrict__ W1,     // [D_CTX+D_Q, H]; uses rows [0, D_CTX)
    const float* __restrict__ b1,     // [H]
    const float* __restrict__ W2,     // [H, 1]
    const float* __restrict__ b2,     // [1]
    const float* __restrict__ stats,  // [B, 4]
    const float* __restrict__ qpart,  // [B, H]
    float* __restrict__ post)         // [B, W]
{
    const int t   = blockIdx.x;  // window slot 0..6
    const int b   = blockIdx.y;
    const int tid = threadIdx.x;
    const int jg  = tid & 63;
    const int kc  = tid >> 6;    // 0..7

    const float alpha  = stats[b * 4 + 0];
    const float beta   = stats[b * 4 + 1];
    const float kappa  = stats[b * 4 + 2];
    const int   center = (int)stats[b * 4 + 3];
    const int   l      = center + PRUNE_L + t;

    if (l < 0 || l >= L) {               // block-uniform branch
        if (tid == 0) post[b * W + t] = 0.0f;
        return;
    }

    __shared__ float  c_sh[D_CTX];       // 2 KB
    __shared__ float4 part[8][64];       // 8 KB
    __shared__ float  red[H];            // 1 KB

    const float4* ctx4 = (const float4*)(ctx + ((size_t)b * L + (size_t)l) * D_CTX);
    if (tid < D_CTX / 4) ((float4*)c_sh)[tid] = ctx4[tid];
    __syncthreads();

    const float4* Wv = (const float4*)W1;
    float4 acc = make_float4(0.f, 0.f, 0.f, 0.f);
    const int k0 = kc * 64;
#pragma unroll 8
    for (int k = k0; k < k0 + 64; ++k) {
        const float  ck = c_sh[k];
        const float4 w  = Wv[k * 64 + jg];
        acc.x += ck * w.x; acc.y += ck * w.y;
        acc.z += ck * w.z; acc.w += ck * w.w;
    }
    part[kc][jg] = acc;
    __syncthreads();
    for (int s = 4; s > 0; s >>= 1) {    // 8-way K-chunk reduce
        if (kc < s) {
            float4 a = part[kc][jg], c = part[kc + s][jg];
            a.x += c.x; a.y += c.y; a.z += c.z; a.w += c.w;
            part[kc][jg] = a;
        }
        __syncthreads();
    }
    if (tid < H) {
        const float pre = ((const float*)part)[tid] + qpart[b * H + tid] + b1[tid];
        red[tid] = tanhf(pre) * W2[tid];
    }
    __syncthreads();
    for (int s = H / 2; s > 0; s >>= 1) {
        if (tid < s) red[tid] += red[tid + s];
        __syncthreads();
    }
    if (tid == 0) {
        const float score = red[0] + b2[0];
        const float diff  = (float)l - kappa;
        post[b * W + t] = expf(score) * alpha * expf(-beta * diff * diff);
    }
}

// ---------------------------------------------------------------------------
// Kernel C: normalize posterior, write p_ctx (zeros + 7-entry scatter) and
// expected_ctx = sum_t p_t * ctx[b, l_t, :].
// grid = B, block = 256
// ---------------------------------------------------------------------------
__global__ __launch_bounds__(256) void combine_kernel(
    const float* __restrict__ ctx,    // [B, L, D_CTX]
    const float* __restrict__ stats,  // [B, 4]
    const float* __restrict__ post,   // [B, W]
    float* __restrict__ out_e,        // [B, D_CTX]
    float* __restrict__ out_p)        // [B, L]
{
    const int b = blockIdx.x;
    const int j = threadIdx.x;

    __shared__ float p_sh[W];
    __shared__ int   l_sh[W];
    if (j == 0) {
        const int center = (int)stats[b * 4 + 3];
        float sum = 0.0f;
        for (int t = 0; t < W; ++t) sum += post[b * W + t];
        const float inv = 1.0f / sum;  // sum==0 -> NaN, same as reference
        for (int t = 0; t < W; ++t) {
            p_sh[t] = post[b * W + t] * inv;
            l_sh[t] = center + PRUNE_L + t;
        }
    }
    __syncthreads();

    // p_ctx row: zero-fill (d_out is poisoned) then scatter the window
    float4* prow = (float4*)(out_p + (size_t)b * L);
    const float4 z = make_float4(0.f, 0.f, 0.f, 0.f);
    prow[j]       = z;                  // 2048 floats = 512 float4, 2 per thread
    prow[j + 256] = z;
    __syncthreads();
    if (j < W) {
        const int l = l_sh[j];
        if (l >= 0 && l < L) out_p[(size_t)b * L + l] = p_sh[j];
    }

    // expected_ctx: 7-term weighted float4 gather (128 float4 = 512 dims)
    if (j < D_CTX / 4) {
        float4 acc = make_float4(0.f, 0.f, 0.f, 0.f);
#pragma unroll
        for (int t = 0; t < W; ++t) {
            const int l = l_sh[t];
            if (l >= 0 && l < L) {
                const float4 c = ((const float4*)(ctx + ((size_t)b * L + (size_t)l) * D_CTX))[j];
                const float  p = p_sh[t];
                acc.x += p * c.x; acc.y += p * c.y;
                acc.z += p * c.z; acc.w += p * c.w;
            }
        }
        ((float4*)(out_e + (size_t)b * D_CTX))[j] = acc;
    }
}

extern "C" void kernel_launch(void* const* d_in, const int* in_sizes, int n_in,
                              void* d_out, int out_size, void* d_ws, size_t ws_size,
                              hipStream_t stream) {
    const float* query      = (const float*)d_in[0];
    const float* ctx        = (const float*)d_in[1];
    const float* kappa_prev = (const float*)d_in[2];
    const float* Wq         = (const float*)d_in[3];
    const float* bq         = (const float*)d_in[4];
    const float* Ws         = (const float*)d_in[5];
    const float* bs         = (const float*)d_in[6];
    const float* W1         = (const float*)d_in[7];
    const float* b1         = (const float*)d_in[8];
    const float* W2         = (const float*)d_in[9];
    const float* b2         = (const float*)d_in[10];

    float* out   = (float*)d_out;
    float* out_e = out;              // [B, D_CTX]
    float* out_p = out + B * D_CTX;  // [B, L]

    float* stats = (float*)d_ws;         // [B, 4]   (qpart offset stays 16B-aligned)
    float* qpart = stats + B * 4;        // [B, H]
    float* post  = qpart + B * H;        // [B, W]

    stats_qpart_kernel<<<B, 1024, 0, stream>>>(query, kappa_prev, Wq, bq, Ws, bs,
                                               W1, stats, qpart);
    score_kernel<<<dim3(W, B), 512, 0, stream>>>(ctx, W1, b1, W2, b2, stats, qpart, post);
    combine_kernel<<<B, 256, 0, stream>>>(ctx, stats, post, out_e, out_p);
}